// Round 1
// baseline (1102.380 us; speedup 1.0000x reference)
//
#include <hip/hip_runtime.h>
#include <math.h>

#define N_SRC   50000
#define N_SAMP  50000
#define N_TOTAL 200000
#define NE      1600000
#define D       256

// Column-blocked CSR: cells indexed (row, col_block). col_block = col >> 12
// (4096 cols = 4 MB of x rows, one XCD-L2's worth).
#define CBSHIFT 12
#define NB      13                 // ceil(50000 / 4096)
#define NCELL   (N_SAMP * NB)      // 650,000 cells

// ---- Pass 1: per-cell edge counts + owner (last-write-wins over dup nodes) ----
__global__ __launch_bounds__(256) void k_count(
    const int* __restrict__ adj_row, const int* __restrict__ adj_col,
    const int* __restrict__ nodes, int* __restrict__ cellcnt, int* __restrict__ owner)
{
    int idx = blockIdx.x * 256 + threadIdx.x;
    if (idx < NE) {
        int row = adj_row[idx];
        int col = adj_col[idx];
        atomicAdd(&cellcnt[row * NB + (col >> CBSHIFT)], 1);
    }
    if (idx < N_SAMP) {
        atomicMax(&owner[nodes[idx]], idx);   // owner init -1
    }
}

// ---- Pass 2: exact allocation. cellend[i] <- begin offset (order-free alloc).
// Block-level scan + one global atomic per block (cell ordering irrelevant:
// regions only need to be disjoint and exact). ----
__global__ __launch_bounds__(256) void k_alloc(
    const int* __restrict__ cellcnt, int* __restrict__ cellend, int* __restrict__ gtotal)
{
    int idx  = blockIdx.x * 256 + threadIdx.x;
    int lane = threadIdx.x & 63;
    int wid  = threadIdx.x >> 6;
    int v = (idx < NCELL) ? cellcnt[idx] : 0;
    // inclusive wave scan
    int s = v;
    #pragma unroll
    for (int d = 1; d < 64; d <<= 1) {
        int t = __shfl_up(s, d, 64);
        if (lane >= d) s += t;
    }
    __shared__ int wbase[4];
    if (lane == 63) wbase[wid] = s;
    __syncthreads();
    if (threadIdx.x == 0) {
        int b0 = wbase[0], b1 = wbase[1], b2 = wbase[2], b3 = wbase[3];
        int base = atomicAdd(gtotal, b0 + b1 + b2 + b3);
        wbase[0] = base;
        wbase[1] = base + b0;
        wbase[2] = base + b0 + b1;
        wbase[3] = base + b0 + b1 + b2;
    }
    __syncthreads();
    if (idx < NCELL) cellend[idx] = wbase[wid] + (s - v);   // exclusive scan = begin
}

// ---- Pass 3: scatter packed {col, val}. cellend[cell] advances begin -> end. ----
__global__ __launch_bounds__(256) void k_scatter(
    const int* __restrict__ adj_row, const int* __restrict__ adj_col,
    const float* __restrict__ adj_val, int* __restrict__ cellend, int2* __restrict__ bucket)
{
    int idx = blockIdx.x * 256 + threadIdx.x;
    if (idx >= NE) return;
    int row = adj_row[idx];
    int col = adj_col[idx];
    float val = adj_val[idx];
    int cell = row * NB + (col >> CBSHIFT);
    int pos = atomicAdd(&cellend[cell], 1);
    bucket[pos] = make_int2(col, __float_as_int(val));
}

// ---- Pass 4: column-phased SpMM + blend + owned new_y rows.
// One wave owns 8 rows; accumulators live in registers across all 13 column
// phases. All ~1563 blocks co-resident -> phases stay time-aligned and each
// phase's 4 MB x-slice stays cache-hot.
__global__ __launch_bounds__(256) void k_spmm_blend(
    const float* __restrict__ x, const int2* __restrict__ bucket,
    const int* __restrict__ cellcnt, const int* __restrict__ cellend,
    const int* __restrict__ nodes, const int* __restrict__ owner,
    const float* __restrict__ y_buf, float* __restrict__ feat, float* __restrict__ newy)
{
    int wave  = threadIdx.x >> 6;
    int lane  = threadIdx.x & 63;
    int wrow0 = (blockIdx.x * 4 + wave) * 8;
    if (wrow0 >= N_SAMP) return;
    int off = lane * 4;

    float4 acc[8];
    #pragma unroll
    for (int i = 0; i < 8; ++i) acc[i] = make_float4(0.f, 0.f, 0.f, 0.f);

    for (int cb = 0; cb < NB; ++cb) {
        #pragma unroll
        for (int rr = 0; rr < 8; ++rr) {
            int row = wrow0 + rr;
            if (row < N_SAMP) {
                int cell = row * NB + cb;
                int cnt  = cellcnt[cell];
                int end  = cellend[cell];
                const int2* bk = bucket + (end - cnt);
                float4 a = acc[rr];
                int j = 0;
                for (; j + 1 < cnt; j += 2) {
                    int2 e0 = bk[j], e1 = bk[j + 1];
                    float v0 = __int_as_float(e0.y), v1 = __int_as_float(e1.y);
                    float4 x0 = *(const float4*)(x + (size_t)e0.x * D + off);
                    float4 x1 = *(const float4*)(x + (size_t)e1.x * D + off);
                    a.x += v0 * x0.x + v1 * x1.x;
                    a.y += v0 * x0.y + v1 * x1.y;
                    a.z += v0 * x0.z + v1 * x1.z;
                    a.w += v0 * x0.w + v1 * x1.w;
                }
                if (j < cnt) {
                    int2 e0 = bk[j];
                    float v0 = __int_as_float(e0.y);
                    float4 x0 = *(const float4*)(x + (size_t)e0.x * D + off);
                    a.x += v0 * x0.x; a.y += v0 * x0.y;
                    a.z += v0 * x0.z; a.w += v0 * x0.w;
                }
                acc[rr] = a;
            }
        }
    }

    #pragma unroll
    for (int rr = 0; rr < 8; ++rr) {
        int row = wrow0 + rr;
        if (row < N_SAMP) {
            int node = nodes[row];
            float4 yv = *(const float4*)(y_buf + (size_t)node * D + off);
            float4 f;
            f.x = 0.9f * yv.x + 0.1f * acc[rr].x;
            f.y = 0.9f * yv.y + 0.1f * acc[rr].y;
            f.z = 0.9f * yv.z + 0.1f * acc[rr].z;
            f.w = 0.9f * yv.w + 0.1f * acc[rr].w;
            *(float4*)(feat + (size_t)row * D + off) = f;
            if (owner[node] == row)
                *(float4*)(newy + (size_t)node * D + off) = f;
        }
    }
}

// ---- Pass 5: decay-only rows (owner < 0); owned rows were written by spmm. ----
__global__ __launch_bounds__(256) void k_newy(
    const float* __restrict__ y_buf, const int* __restrict__ owner,
    float* __restrict__ newy)
{
    int wave = threadIdx.x >> 6;
    int lane = threadIdx.x & 63;
    int row  = blockIdx.x * 4 + wave;
    if (row >= N_TOTAL) return;
    if (owner[row] >= 0) return;          // wave-uniform branch
    int off = lane * 4;
    float4 y = *(const float4*)(y_buf + (size_t)row * D + off);
    float4 r = make_float4(0.9f * y.x, 0.9f * y.y, 0.9f * y.z, 0.9f * y.w);
    *(float4*)(newy + (size_t)row * D + off) = r;
}

// ---- Pass 6: in-place feat -> elu(feat@W+b) -> per-row norm, fused (unchanged) ----
__global__ __launch_bounds__(256) void k_gemm_elu_norm(
    float* __restrict__ io, const float* __restrict__ Wm,
    const float* __restrict__ b, const float* __restrict__ scale,
    const float* __restrict__ offset)
{
    __shared__ float ldsF[32][256];
    __shared__ float ldsW[32][256];
    int t    = threadIdx.x;
    int quad = t >> 6;
    int lane = t & 63;
    int r0   = blockIdx.x * 32;

    #pragma unroll
    for (int p = 0; p < 8; ++p) {
        int m  = p * 4 + quad;
        int c4 = lane * 4;
        int r  = r0 + m;
        float4 v = (r < N_SAMP) ? *(const float4*)(io + (size_t)r * D + c4)
                                : make_float4(0.f, 0.f, 0.f, 0.f);
        *(float4*)&ldsF[m][c4] = v;
    }

    int m0 = quad * 8;
    int c0 = lane * 4;
    float acc[8][4];
    #pragma unroll
    for (int mm = 0; mm < 8; ++mm)
        for (int i = 0; i < 4; ++i) acc[mm][i] = 0.f;

    for (int kt = 0; kt < 256; kt += 32) {
        __syncthreads();
        #pragma unroll
        for (int p = 0; p < 8; ++p) {
            int kk = p * 4 + quad;
            int c4 = lane * 4;
            *(float4*)&ldsW[kk][c4] = *(const float4*)(Wm + (size_t)(kt + kk) * D + c4);
        }
        __syncthreads();
        #pragma unroll
        for (int k = 0; k < 32; ++k) {
            float4 wv = *(float4*)&ldsW[k][c0];
            #pragma unroll
            for (int mm = 0; mm < 8; ++mm) {
                float fm = ldsF[m0 + mm][kt + k];
                acc[mm][0] += fm * wv.x;
                acc[mm][1] += fm * wv.y;
                acc[mm][2] += fm * wv.z;
                acc[mm][3] += fm * wv.w;
            }
        }
    }

    float4 bv = *(const float4*)(b + c0);
    float4 sv = *(const float4*)(scale + c0);
    float4 ov = *(const float4*)(offset + c0);

    #pragma unroll
    for (int mm = 0; mm < 8; ++mm) {
        float o0 = acc[mm][0] + bv.x;
        float o1 = acc[mm][1] + bv.y;
        float o2 = acc[mm][2] + bv.z;
        float o3 = acc[mm][3] + bv.w;
        o0 = o0 > 0.f ? o0 : expf(o0) - 1.f;
        o1 = o1 > 0.f ? o1 : expf(o1) - 1.f;
        o2 = o2 > 0.f ? o2 : expf(o2) - 1.f;
        o3 = o3 > 0.f ? o3 : expf(o3) - 1.f;
        float s = o0 + o1 + o2 + o3;
        float q = o0 * o0 + o1 * o1 + o2 * o2 + o3 * o3;
        #pragma unroll
        for (int d2 = 1; d2 < 64; d2 <<= 1) {
            s += __shfl_xor(s, d2, 64);
            q += __shfl_xor(q, d2, 64);
        }
        float mean = s * (1.0f / 256.0f);
        float var  = q * (1.0f / 256.0f) - mean * mean + 1e-9f;
        float rstd = rsqrtf(var);
        int r = r0 + m0 + mm;
        if (r < N_SAMP) {
            float4 res;
            res.x = (o0 - mean) * sv.x * rstd + ov.x;
            res.y = (o1 - mean) * sv.y * rstd + ov.y;
            res.z = (o2 - mean) * sv.z * rstd + ov.z;
            res.w = (o3 - mean) * sv.w * rstd + ov.w;
            *(float4*)(io + (size_t)r * D + c0) = res;
        }
    }
}

extern "C" void kernel_launch(void* const* d_in, const int* in_sizes, int n_in,
                              void* d_out, int out_size, void* d_ws, size_t ws_size,
                              hipStream_t stream) {
    const float* x       = (const float*)d_in[0];
    const int*   adj_row = (const int*)  d_in[1];
    const int*   adj_col = (const int*)  d_in[2];
    const float* adj_val = (const float*)d_in[3];
    const int*   nodes   = (const int*)  d_in[4];
    const float* y_buf   = (const float*)d_in[5];
    const float* Wm      = (const float*)d_in[6];
    const float* b       = (const float*)d_in[7];
    const float* scale   = (const float*)d_in[8];
    const float* offset  = (const float*)d_in[9];

    float* out  = (float*)d_out;                  // [N_SAMP, D] (feat staged here first)
    float* newy = out + (size_t)N_SAMP * D;       // [N_TOTAL, D]

    // workspace: cellcnt (2.6MB) | cellend (2.6MB) | gtotal | owner (0.8MB) | bucket (12.8MB)
    char* ws      = (char*)d_ws;
    int*  cellcnt = (int*)ws;                                   // NCELL ints
    int*  cellend = (int*)(ws + 3 * 1024 * 1024);               // NCELL ints
    int*  gtotal  = (int*)(ws + 6 * 1024 * 1024);               // 1 int
    int*  owner   = (int*)(ws + 6 * 1024 * 1024 + 4096);        // N_TOTAL ints
    int2* bucket  = (int2*)(ws + 8 * 1024 * 1024);              // NE int2 (12.8MB)

    hipMemsetAsync(cellcnt, 0,    NCELL   * sizeof(int), stream);
    hipMemsetAsync(gtotal,  0,    sizeof(int), stream);
    hipMemsetAsync(owner,   0xFF, N_TOTAL * sizeof(int), stream);  // owner = -1

    k_count  <<<(NE + 255) / 256,    256, 0, stream>>>(adj_row, adj_col, nodes, cellcnt, owner);
    k_alloc  <<<(NCELL + 255) / 256, 256, 0, stream>>>(cellcnt, cellend, gtotal);
    k_scatter<<<(NE + 255) / 256,    256, 0, stream>>>(adj_row, adj_col, adj_val, cellend, bucket);
    k_spmm_blend<<<(N_SAMP + 31) / 32, 256, 0, stream>>>(
        x, bucket, cellcnt, cellend, nodes, owner, y_buf, out, newy);
    k_newy<<<(N_TOTAL + 3) / 4, 256, 0, stream>>>(y_buf, owner, newy);
    k_gemm_elu_norm<<<(N_SAMP + 31) / 32, 256, 0, stream>>>(out, Wm, b, scale, offset);
}

// Round 2
// 1001.248 us; speedup vs baseline: 1.1010x; 1.1010x over previous
//
#include <hip/hip_runtime.h>
#include <math.h>

#define N_SRC   50000
#define N_SAMP  50000
#define N_TOTAL 200000
#define NE      1600000
#define D       256

// Edges sorted by (row, col>>CBSHIFT), stored contiguously per row.
// 4096 cols = 4 MB of x rows = one XCD-L2's worth per column phase.
#define CBSHIFT 12
#define NB      13                 // ceil(50000 / 4096)
#define NCELL   (N_SAMP * NB)

// ---- Pass 1: per-(row,colblock) counts + owner (last-write-wins) ----
__global__ __launch_bounds__(256) void k_count(
    const int* __restrict__ adj_row, const int* __restrict__ adj_col,
    const int* __restrict__ nodes, int* __restrict__ cellcnt, int* __restrict__ owner)
{
    int idx = blockIdx.x * 256 + threadIdx.x;
    if (idx < NE) {
        int row = adj_row[idx];
        int col = adj_col[idx];
        atomicAdd(&cellcnt[row * NB + (col >> CBSHIFT)], 1);
    }
    if (idx < N_SAMP) {
        atomicMax(&owner[nodes[idx]], idx);   // owner init -1
    }
}

// ---- Pass 2: one thread per row: contiguous region per row (order-free
// atomic alloc), cb-sorted sub-offsets computed in-thread. ----
__global__ __launch_bounds__(256) void k_rowalloc(
    const int* __restrict__ cellcnt, int* __restrict__ cellcur,
    int* __restrict__ rowptr, int* __restrict__ rowcnt, int* __restrict__ gtotal)
{
    int r = blockIdx.x * 256 + threadIdx.x;
    if (r >= N_SAMP) return;
    int pref[NB];
    int sum = 0;
    #pragma unroll
    for (int cb = 0; cb < NB; ++cb) {
        pref[cb] = sum;
        sum += cellcnt[r * NB + cb];
    }
    int base = atomicAdd(gtotal, sum);   // region order across rows irrelevant
    rowptr[r] = base;
    rowcnt[r] = sum;
    #pragma unroll
    for (int cb = 0; cb < NB; ++cb)
        cellcur[r * NB + cb] = base + pref[cb];
}

// ---- Pass 3: scatter packed {col, val}; cellcur advances begin -> end ----
__global__ __launch_bounds__(256) void k_scatter(
    const int* __restrict__ adj_row, const int* __restrict__ adj_col,
    const float* __restrict__ adj_val, int* __restrict__ cellcur, int2* __restrict__ bucket)
{
    int idx = blockIdx.x * 256 + threadIdx.x;
    if (idx >= NE) return;
    int row = adj_row[idx];
    int col = adj_col[idx];
    float val = adj_val[idx];
    int pos = atomicAdd(&cellcur[row * NB + (col >> CBSHIFT)], 1);
    bucket[pos] = make_int2(col, __float_as_int(val));
}

// ---- Pass 4: SpMM, one wave per row, cb-sorted linear edge stream.
// 50000 waves -> full occupancy; 4-wide unroll -> 4 independent gather chains.
// Fused: momentum blend + owned new_y row write. ----
__global__ __launch_bounds__(256) void k_spmm_blend(
    const float* __restrict__ x, const int2* __restrict__ bucket,
    const int* __restrict__ rowptr, const int* __restrict__ rowcnt,
    const int* __restrict__ nodes, const int* __restrict__ owner,
    const float* __restrict__ y_buf, float* __restrict__ feat, float* __restrict__ newy)
{
    int wave = threadIdx.x >> 6;
    int lane = threadIdx.x & 63;
    int row  = blockIdx.x * 4 + wave;
    if (row >= N_SAMP) return;
    int cnt = rowcnt[row];
    const int2* bk = bucket + rowptr[row];
    int off = lane * 4;
    float4 acc = make_float4(0.f, 0.f, 0.f, 0.f);
    int j = 0;
    for (; j + 3 < cnt; j += 4) {
        int2 e0 = bk[j],     e1 = bk[j + 1];
        int2 e2 = bk[j + 2], e3 = bk[j + 3];
        float v0 = __int_as_float(e0.y), v1 = __int_as_float(e1.y);
        float v2 = __int_as_float(e2.y), v3 = __int_as_float(e3.y);
        float4 x0 = *(const float4*)(x + (size_t)e0.x * D + off);
        float4 x1 = *(const float4*)(x + (size_t)e1.x * D + off);
        float4 x2 = *(const float4*)(x + (size_t)e2.x * D + off);
        float4 x3 = *(const float4*)(x + (size_t)e3.x * D + off);
        acc.x += v0 * x0.x + v1 * x1.x + v2 * x2.x + v3 * x3.x;
        acc.y += v0 * x0.y + v1 * x1.y + v2 * x2.y + v3 * x3.y;
        acc.z += v0 * x0.z + v1 * x1.z + v2 * x2.z + v3 * x3.z;
        acc.w += v0 * x0.w + v1 * x1.w + v2 * x2.w + v3 * x3.w;
    }
    for (; j < cnt; ++j) {
        int2 e0 = bk[j];
        float v0 = __int_as_float(e0.y);
        float4 x0 = *(const float4*)(x + (size_t)e0.x * D + off);
        acc.x += v0 * x0.x; acc.y += v0 * x0.y;
        acc.z += v0 * x0.z; acc.w += v0 * x0.w;
    }
    int node = nodes[row];
    float4 yv = *(const float4*)(y_buf + (size_t)node * D + off);
    float4 f;
    f.x = 0.9f * yv.x + 0.1f * acc.x;
    f.y = 0.9f * yv.y + 0.1f * acc.y;
    f.z = 0.9f * yv.z + 0.1f * acc.z;
    f.w = 0.9f * yv.w + 0.1f * acc.w;
    *(float4*)(feat + (size_t)row * D + off) = f;
    if (owner[node] == row)
        *(float4*)(newy + (size_t)node * D + off) = f;
}

// ---- Pass 5: decay-only rows (owner < 0); owned rows written by spmm ----
__global__ __launch_bounds__(256) void k_newy(
    const float* __restrict__ y_buf, const int* __restrict__ owner,
    float* __restrict__ newy)
{
    int wave = threadIdx.x >> 6;
    int lane = threadIdx.x & 63;
    int row  = blockIdx.x * 4 + wave;
    if (row >= N_TOTAL) return;
    if (owner[row] >= 0) return;          // wave-uniform branch
    int off = lane * 4;
    float4 y = *(const float4*)(y_buf + (size_t)row * D + off);
    float4 r = make_float4(0.9f * y.x, 0.9f * y.y, 0.9f * y.z, 0.9f * y.w);
    *(float4*)(newy + (size_t)row * D + off) = r;
}

// ---- Pass 6: in-place feat -> elu(feat@W+b) -> per-row norm, fused ----
__global__ __launch_bounds__(256) void k_gemm_elu_norm(
    float* __restrict__ io, const float* __restrict__ Wm,
    const float* __restrict__ b, const float* __restrict__ scale,
    const float* __restrict__ offset)
{
    __shared__ float ldsF[32][256];
    __shared__ float ldsW[32][256];
    int t    = threadIdx.x;
    int quad = t >> 6;
    int lane = t & 63;
    int r0   = blockIdx.x * 32;

    #pragma unroll
    for (int p = 0; p < 8; ++p) {
        int m  = p * 4 + quad;
        int c4 = lane * 4;
        int r  = r0 + m;
        float4 v = (r < N_SAMP) ? *(const float4*)(io + (size_t)r * D + c4)
                                : make_float4(0.f, 0.f, 0.f, 0.f);
        *(float4*)&ldsF[m][c4] = v;
    }

    int m0 = quad * 8;
    int c0 = lane * 4;
    float acc[8][4];
    #pragma unroll
    for (int mm = 0; mm < 8; ++mm)
        for (int i = 0; i < 4; ++i) acc[mm][i] = 0.f;

    for (int kt = 0; kt < 256; kt += 32) {
        __syncthreads();
        #pragma unroll
        for (int p = 0; p < 8; ++p) {
            int kk = p * 4 + quad;
            int c4 = lane * 4;
            *(float4*)&ldsW[kk][c4] = *(const float4*)(Wm + (size_t)(kt + kk) * D + c4);
        }
        __syncthreads();
        #pragma unroll
        for (int k = 0; k < 32; ++k) {
            float4 wv = *(float4*)&ldsW[k][c0];
            #pragma unroll
            for (int mm = 0; mm < 8; ++mm) {
                float fm = ldsF[m0 + mm][kt + k];
                acc[mm][0] += fm * wv.x;
                acc[mm][1] += fm * wv.y;
                acc[mm][2] += fm * wv.z;
                acc[mm][3] += fm * wv.w;
            }
        }
    }

    float4 bv = *(const float4*)(b + c0);
    float4 sv = *(const float4*)(scale + c0);
    float4 ov = *(const float4*)(offset + c0);

    #pragma unroll
    for (int mm = 0; mm < 8; ++mm) {
        float o0 = acc[mm][0] + bv.x;
        float o1 = acc[mm][1] + bv.y;
        float o2 = acc[mm][2] + bv.z;
        float o3 = acc[mm][3] + bv.w;
        o0 = o0 > 0.f ? o0 : expf(o0) - 1.f;
        o1 = o1 > 0.f ? o1 : expf(o1) - 1.f;
        o2 = o2 > 0.f ? o2 : expf(o2) - 1.f;
        o3 = o3 > 0.f ? o3 : expf(o3) - 1.f;
        float s = o0 + o1 + o2 + o3;
        float q = o0 * o0 + o1 * o1 + o2 * o2 + o3 * o3;
        #pragma unroll
        for (int d2 = 1; d2 < 64; d2 <<= 1) {
            s += __shfl_xor(s, d2, 64);
            q += __shfl_xor(q, d2, 64);
        }
        float mean = s * (1.0f / 256.0f);
        float var  = q * (1.0f / 256.0f) - mean * mean + 1e-9f;
        float rstd = rsqrtf(var);
        int r = r0 + m0 + mm;
        if (r < N_SAMP) {
            float4 res;
            res.x = (o0 - mean) * sv.x * rstd + ov.x;
            res.y = (o1 - mean) * sv.y * rstd + ov.y;
            res.z = (o2 - mean) * sv.z * rstd + ov.z;
            res.w = (o3 - mean) * sv.w * rstd + ov.w;
            *(float4*)(io + (size_t)r * D + c0) = res;
        }
    }
}

extern "C" void kernel_launch(void* const* d_in, const int* in_sizes, int n_in,
                              void* d_out, int out_size, void* d_ws, size_t ws_size,
                              hipStream_t stream) {
    const float* x       = (const float*)d_in[0];
    const int*   adj_row = (const int*)  d_in[1];
    const int*   adj_col = (const int*)  d_in[2];
    const float* adj_val = (const float*)d_in[3];
    const int*   nodes   = (const int*)  d_in[4];
    const float* y_buf   = (const float*)d_in[5];
    const float* Wm      = (const float*)d_in[6];
    const float* b       = (const float*)d_in[7];
    const float* scale   = (const float*)d_in[8];
    const float* offset  = (const float*)d_in[9];

    float* out  = (float*)d_out;                  // [N_SAMP, D] (feat staged here first)
    float* newy = out + (size_t)N_SAMP * D;       // [N_TOTAL, D]

    // workspace layout
    char* ws      = (char*)d_ws;
    int*  cellcnt = (int*)(ws);                          // NCELL ints (2.6 MB)
    int*  cellcur = (int*)(ws + 3  * 1024 * 1024);       // NCELL ints (2.6 MB)
    int*  rowptr  = (int*)(ws + 6  * 1024 * 1024);       // N_SAMP ints (200 KB)
    int*  rowcnt  = (int*)(ws + 6  * 1024 * 1024 + 256 * 1024);   // N_SAMP ints
    int*  gtotal  = (int*)(ws + 6  * 1024 * 1024 + 512 * 1024);   // 1 int
    int*  owner   = (int*)(ws + 7  * 1024 * 1024);       // N_TOTAL ints (800 KB)
    int2* bucket  = (int2*)(ws + 8 * 1024 * 1024);       // NE int2 (12.8 MB)

    hipMemsetAsync(cellcnt, 0,    NCELL   * sizeof(int), stream);
    hipMemsetAsync(gtotal,  0,    sizeof(int), stream);
    hipMemsetAsync(owner,   0xFF, N_TOTAL * sizeof(int), stream);  // owner = -1

    k_count   <<<(NE + 255) / 256,     256, 0, stream>>>(adj_row, adj_col, nodes, cellcnt, owner);
    k_rowalloc<<<(N_SAMP + 255) / 256, 256, 0, stream>>>(cellcnt, cellcur, rowptr, rowcnt, gtotal);
    k_scatter <<<(NE + 255) / 256,     256, 0, stream>>>(adj_row, adj_col, adj_val, cellcur, bucket);
    k_spmm_blend<<<(N_SAMP + 3) / 4, 256, 0, stream>>>(
        x, bucket, rowptr, rowcnt, nodes, owner, y_buf, out, newy);
    k_newy<<<(N_TOTAL + 3) / 4, 256, 0, stream>>>(y_buf, owner, newy);
    k_gemm_elu_norm<<<(N_SAMP + 31) / 32, 256, 0, stream>>>(out, Wm, b, scale, offset);
}

// Round 3
// 975.885 us; speedup vs baseline: 1.1296x; 1.0260x over previous
//
#include <hip/hip_runtime.h>
#include <math.h>

#define N_SRC   50000
#define N_SAMP  50000
#define N_TOTAL 200000
#define NE      1600000
#define D       256

// Edges sorted by (row, col>>CBSHIFT), stored contiguously per row.
#define CBSHIFT 12
#define NB      13                 // ceil(50000 / 4096)
#define NCELL   (N_SAMP * NB)

// ---- nontemporal helpers (keep L3 for x + W; stream everything read/written once)
typedef float f32x4 __attribute__((ext_vector_type(4)));

__device__ __forceinline__ float4 ntload4(const float* p) {
    f32x4 t = __builtin_nontemporal_load((const f32x4*)p);
    return make_float4(t.x, t.y, t.z, t.w);
}
__device__ __forceinline__ void ntstore4(float* p, float4 v) {
    f32x4 t; t.x = v.x; t.y = v.y; t.z = v.z; t.w = v.w;
    __builtin_nontemporal_store(t, (f32x4*)p);
}

// ---- Pass 0: fused init (replaces 3 memsets) ----
__global__ __launch_bounds__(256) void k_init(
    int* __restrict__ cellcnt, int* __restrict__ owner, int* __restrict__ gtotal)
{
    int i = blockIdx.x * 256 + threadIdx.x;
    if (i < NCELL)   cellcnt[i] = 0;
    if (i < N_TOTAL) owner[i]   = -1;
    if (i == 0)      *gtotal    = 0;
}

// ---- Pass 1: per-(row,colblock) counts + owner (last-write-wins) ----
__global__ __launch_bounds__(256) void k_count(
    const int* __restrict__ adj_row, const int* __restrict__ adj_col,
    const int* __restrict__ nodes, int* __restrict__ cellcnt, int* __restrict__ owner)
{
    int idx = blockIdx.x * 256 + threadIdx.x;
    if (idx < NE) {
        int row = adj_row[idx];
        int col = adj_col[idx];
        atomicAdd(&cellcnt[row * NB + (col >> CBSHIFT)], 1);
    }
    if (idx < N_SAMP) {
        atomicMax(&owner[nodes[idx]], idx);   // owner init -1
    }
}

// ---- Pass 2: one thread per row: contiguous region per row (order-free
// atomic alloc), cb-sorted sub-offsets computed in-thread. ----
__global__ __launch_bounds__(256) void k_rowalloc(
    const int* __restrict__ cellcnt, int* __restrict__ cellcur,
    int* __restrict__ rowptr, int* __restrict__ rowcnt, int* __restrict__ gtotal)
{
    int r = blockIdx.x * 256 + threadIdx.x;
    if (r >= N_SAMP) return;
    int pref[NB];
    int sum = 0;
    #pragma unroll
    for (int cb = 0; cb < NB; ++cb) {
        pref[cb] = sum;
        sum += cellcnt[r * NB + cb];
    }
    int base = atomicAdd(gtotal, sum);   // region order across rows irrelevant
    rowptr[r] = base;
    rowcnt[r] = sum;
    #pragma unroll
    for (int cb = 0; cb < NB; ++cb)
        cellcur[r * NB + cb] = base + pref[cb];
}

// ---- Pass 3: scatter packed {col, val}; cellcur advances begin -> end ----
__global__ __launch_bounds__(256) void k_scatter(
    const int* __restrict__ adj_row, const int* __restrict__ adj_col,
    const float* __restrict__ adj_val, int* __restrict__ cellcur, int2* __restrict__ bucket)
{
    int idx = blockIdx.x * 256 + threadIdx.x;
    if (idx >= NE) return;
    int row = adj_row[idx];
    int col = adj_col[idx];
    float val = adj_val[idx];
    int pos = atomicAdd(&cellcur[row * NB + (col >> CBSHIFT)], 1);
    bucket[pos] = make_int2(col, __float_as_int(val));
}

// ---- Pass 4: SpMM (one wave per row, cb-sorted linear stream, 4-wide ILP)
//              + momentum blend + owned new_y write
//              + fused decay rows: wave `row` owns newy rows 4row..4row+3.
// Grid = exactly 12500 blocks x 4 waves = 50000 waves; 50000*4 = 200000. ----
__global__ __launch_bounds__(256) void k_spmm_blend(
    const float* __restrict__ x, const int2* __restrict__ bucket,
    const int* __restrict__ rowptr, const int* __restrict__ rowcnt,
    const int* __restrict__ nodes, const int* __restrict__ owner,
    const float* __restrict__ y_buf, float* __restrict__ feat, float* __restrict__ newy)
{
    int wave = threadIdx.x >> 6;
    int lane = threadIdx.x & 63;
    int row  = blockIdx.x * 4 + wave;      // always < N_SAMP (grid exact)
    int off  = lane * 4;

    int cnt = rowcnt[row];
    const int2* bk = bucket + rowptr[row];
    float4 acc = make_float4(0.f, 0.f, 0.f, 0.f);
    int j = 0;
    for (; j + 3 < cnt; j += 4) {
        int2 e0 = bk[j],     e1 = bk[j + 1];
        int2 e2 = bk[j + 2], e3 = bk[j + 3];
        float v0 = __int_as_float(e0.y), v1 = __int_as_float(e1.y);
        float v2 = __int_as_float(e2.y), v3 = __int_as_float(e3.y);
        float4 x0 = *(const float4*)(x + (size_t)e0.x * D + off);
        float4 x1 = *(const float4*)(x + (size_t)e1.x * D + off);
        float4 x2 = *(const float4*)(x + (size_t)e2.x * D + off);
        float4 x3 = *(const float4*)(x + (size_t)e3.x * D + off);
        acc.x += v0 * x0.x + v1 * x1.x + v2 * x2.x + v3 * x3.x;
        acc.y += v0 * x0.y + v1 * x1.y + v2 * x2.y + v3 * x3.y;
        acc.z += v0 * x0.z + v1 * x1.z + v2 * x2.z + v3 * x3.z;
        acc.w += v0 * x0.w + v1 * x1.w + v2 * x2.w + v3 * x3.w;
    }
    for (; j < cnt; ++j) {
        int2 e0 = bk[j];
        float v0 = __int_as_float(e0.y);
        float4 x0 = *(const float4*)(x + (size_t)e0.x * D + off);
        acc.x += v0 * x0.x; acc.y += v0 * x0.y;
        acc.z += v0 * x0.z; acc.w += v0 * x0.w;
    }
    int node = nodes[row];
    float4 yv = ntload4(y_buf + (size_t)node * D + off);
    float4 f;
    f.x = 0.9f * yv.x + 0.1f * acc.x;
    f.y = 0.9f * yv.y + 0.1f * acc.y;
    f.z = 0.9f * yv.z + 0.1f * acc.z;
    f.w = 0.9f * yv.w + 0.1f * acc.w;
    *(float4*)(feat + (size_t)row * D + off) = f;   // re-read by gemm: keep cached
    if (owner[node] == row)
        ntstore4(newy + (size_t)node * D + off, f);

    // ---- fused decay rows (owner < 0): streaming work fills idle BW ----
    int base = row * 4;
    int4 ow = *(const int4*)&owner[base];
    #pragma unroll
    for (int k = 0; k < 4; ++k) {
        int o = (k == 0) ? ow.x : (k == 1) ? ow.y : (k == 2) ? ow.z : ow.w;
        if (o < 0) {
            int r = base + k;
            float4 y = ntload4(y_buf + (size_t)r * D + off);
            ntstore4(newy + (size_t)r * D + off,
                     make_float4(0.9f * y.x, 0.9f * y.y, 0.9f * y.z, 0.9f * y.w));
        }
    }
}

// ---- Pass 5: in-place feat -> elu(feat@W+b) -> per-row norm, fused ----
__global__ __launch_bounds__(256) void k_gemm_elu_norm(
    float* __restrict__ io, const float* __restrict__ Wm,
    const float* __restrict__ b, const float* __restrict__ scale,
    const float* __restrict__ offset)
{
    __shared__ float ldsF[32][256];
    __shared__ float ldsW[32][256];
    int t    = threadIdx.x;
    int quad = t >> 6;
    int lane = t & 63;
    int r0   = blockIdx.x * 32;

    #pragma unroll
    for (int p = 0; p < 8; ++p) {
        int m  = p * 4 + quad;
        int c4 = lane * 4;
        int r  = r0 + m;
        float4 v = (r < N_SAMP) ? ntload4(io + (size_t)r * D + c4)   // read-once stream
                                : make_float4(0.f, 0.f, 0.f, 0.f);
        *(float4*)&ldsF[m][c4] = v;
    }

    int m0 = quad * 8;
    int c0 = lane * 4;
    float acc[8][4];
    #pragma unroll
    for (int mm = 0; mm < 8; ++mm)
        for (int i = 0; i < 4; ++i) acc[mm][i] = 0.f;

    for (int kt = 0; kt < 256; kt += 32) {
        __syncthreads();
        #pragma unroll
        for (int p = 0; p < 8; ++p) {
            int kk = p * 4 + quad;
            int c4 = lane * 4;
            *(float4*)&ldsW[kk][c4] = *(const float4*)(Wm + (size_t)(kt + kk) * D + c4);
        }
        __syncthreads();
        #pragma unroll
        for (int k = 0; k < 32; ++k) {
            float4 wv = *(float4*)&ldsW[k][c0];
            #pragma unroll
            for (int mm = 0; mm < 8; ++mm) {
                float fm = ldsF[m0 + mm][kt + k];
                acc[mm][0] += fm * wv.x;
                acc[mm][1] += fm * wv.y;
                acc[mm][2] += fm * wv.z;
                acc[mm][3] += fm * wv.w;
            }
        }
    }

    float4 bv = *(const float4*)(b + c0);
    float4 sv = *(const float4*)(scale + c0);
    float4 ov = *(const float4*)(offset + c0);

    #pragma unroll
    for (int mm = 0; mm < 8; ++mm) {
        float o0 = acc[mm][0] + bv.x;
        float o1 = acc[mm][1] + bv.y;
        float o2 = acc[mm][2] + bv.z;
        float o3 = acc[mm][3] + bv.w;
        o0 = o0 > 0.f ? o0 : expf(o0) - 1.f;
        o1 = o1 > 0.f ? o1 : expf(o1) - 1.f;
        o2 = o2 > 0.f ? o2 : expf(o2) - 1.f;
        o3 = o3 > 0.f ? o3 : expf(o3) - 1.f;
        float s = o0 + o1 + o2 + o3;
        float q = o0 * o0 + o1 * o1 + o2 * o2 + o3 * o3;
        #pragma unroll
        for (int d2 = 1; d2 < 64; d2 <<= 1) {
            s += __shfl_xor(s, d2, 64);
            q += __shfl_xor(q, d2, 64);
        }
        float mean = s * (1.0f / 256.0f);
        float var  = q * (1.0f / 256.0f) - mean * mean + 1e-9f;
        float rstd = rsqrtf(var);
        int r = r0 + m0 + mm;
        if (r < N_SAMP) {
            float4 res;
            res.x = (o0 - mean) * sv.x * rstd + ov.x;
            res.y = (o1 - mean) * sv.y * rstd + ov.y;
            res.z = (o2 - mean) * sv.z * rstd + ov.z;
            res.w = (o3 - mean) * sv.w * rstd + ov.w;
            ntstore4(io + (size_t)r * D + c0, res);   // final output: don't cache
        }
    }
}

extern "C" void kernel_launch(void* const* d_in, const int* in_sizes, int n_in,
                              void* d_out, int out_size, void* d_ws, size_t ws_size,
                              hipStream_t stream) {
    const float* x       = (const float*)d_in[0];
    const int*   adj_row = (const int*)  d_in[1];
    const int*   adj_col = (const int*)  d_in[2];
    const float* adj_val = (const float*)d_in[3];
    const int*   nodes   = (const int*)  d_in[4];
    const float* y_buf   = (const float*)d_in[5];
    const float* Wm      = (const float*)d_in[6];
    const float* b       = (const float*)d_in[7];
    const float* scale   = (const float*)d_in[8];
    const float* offset  = (const float*)d_in[9];

    float* out  = (float*)d_out;                  // [N_SAMP, D] (feat staged here first)
    float* newy = out + (size_t)N_SAMP * D;       // [N_TOTAL, D]

    // workspace layout
    char* ws      = (char*)d_ws;
    int*  cellcnt = (int*)(ws);                          // NCELL ints (2.6 MB)
    int*  cellcur = (int*)(ws + 3  * 1024 * 1024);       // NCELL ints (2.6 MB)
    int*  rowptr  = (int*)(ws + 6  * 1024 * 1024);       // N_SAMP ints (200 KB)
    int*  rowcnt  = (int*)(ws + 6  * 1024 * 1024 + 256 * 1024);   // N_SAMP ints
    int*  gtotal  = (int*)(ws + 6  * 1024 * 1024 + 512 * 1024);   // 1 int
    int*  owner   = (int*)(ws + 7  * 1024 * 1024);       // N_TOTAL ints (800 KB)
    int2* bucket  = (int2*)(ws + 8 * 1024 * 1024);       // NE int2 (12.8 MB)

    k_init    <<<(NCELL + 255) / 256,  256, 0, stream>>>(cellcnt, owner, gtotal);
    k_count   <<<(NE + 255) / 256,     256, 0, stream>>>(adj_row, adj_col, nodes, cellcnt, owner);
    k_rowalloc<<<(N_SAMP + 255) / 256, 256, 0, stream>>>(cellcnt, cellcur, rowptr, rowcnt, gtotal);
    k_scatter <<<(NE + 255) / 256,     256, 0, stream>>>(adj_row, adj_col, adj_val, cellcur, bucket);
    k_spmm_blend<<<N_SAMP / 4, 256, 0, stream>>>(
        x, bucket, rowptr, rowcnt, nodes, owner, y_buf, out, newy);
    k_gemm_elu_norm<<<(N_SAMP + 31) / 32, 256, 0, stream>>>(out, Wm, b, scale, offset);
}

// Round 4
// 837.029 us; speedup vs baseline: 1.3170x; 1.1659x over previous
//
#include <hip/hip_runtime.h>
#include <hip/hip_fp16.h>
#include <math.h>

#define N_SRC   50000
#define N_SAMP  50000
#define N_TOTAL 200000
#define NE      1600000
#define D       256

// Edges sorted by (row, col>>CBSHIFT), stored contiguously per row.
#define CBSHIFT 12
#define NB      13                 // ceil(50000 / 4096)
#define NCELL   (N_SAMP * NB)

typedef unsigned short ushort;
typedef unsigned int   uint;
using bf16x8 = __attribute__((ext_vector_type(8))) short;
using f32x4v = __attribute__((ext_vector_type(4))) float;

// ---- nontemporal helpers (streaming reads/writes) ----
__device__ __forceinline__ float4 ntload4(const float* p) {
    f32x4v t = __builtin_nontemporal_load((const f32x4v*)p);
    return make_float4(t.x, t.y, t.z, t.w);
}
__device__ __forceinline__ void ntstore4(float* p, float4 v) {
    f32x4v t; t.x = v.x; t.y = v.y; t.z = v.z; t.w = v.w;
    __builtin_nontemporal_store(t, (f32x4v*)p);
}

// ---- bf16 round-to-nearest-even split helpers ----
__device__ __forceinline__ ushort bf16_rne(float f) {
    uint u = __float_as_uint(f);
    uint r = u + 0x7FFFu + ((u >> 16) & 1u);
    return (ushort)(r >> 16);
}
__device__ __forceinline__ float bf16_tof(ushort h) {
    return __uint_as_float(((uint)h) << 16);
}

// ---- fp16 x gather load: 8 B/lane -> float4 ----
__device__ __forceinline__ float4 xload4h(const __half* p) {
    int2 r = *(const int2*)p;
    __half2 h0 = *(__half2*)&r.x;
    __half2 h1 = *(__half2*)&r.y;
    float2 f0 = __half22float2(h0);
    float2 f1 = __half22float2(h1);
    return make_float4(f0.x, f0.y, f1.x, f1.y);
}

// ---- Pass 0: fused init ----
__global__ __launch_bounds__(256) void k_init(
    int* __restrict__ cellcnt, int* __restrict__ owner, int* __restrict__ gtotal)
{
    int i = blockIdx.x * 256 + threadIdx.x;
    if (i < NCELL)   cellcnt[i] = 0;
    if (i < N_TOTAL) owner[i]   = -1;
    if (i == 0)      *gtotal    = 0;
}

// ---- Pass 0b: x -> fp16 (halves gather bytes in spmm) ----
__global__ __launch_bounds__(256) void k_prep(
    const float* __restrict__ x, __half* __restrict__ xh)
{
    int i = blockIdx.x * 256 + threadIdx.x;   // one thread = 8 elements
    if (i >= (N_SRC * D) / 8) return;
    const float4* p = (const float4*)x + (size_t)i * 2;
    float4 a = p[0], c = p[1];
    __half2 h0 = __floats2half2_rn(a.x, a.y);
    __half2 h1 = __floats2half2_rn(a.z, a.w);
    __half2 h2 = __floats2half2_rn(c.x, c.y);
    __half2 h3 = __floats2half2_rn(c.z, c.w);
    int4 w;
    w.x = *(int*)&h0; w.y = *(int*)&h1; w.z = *(int*)&h2; w.w = *(int*)&h3;
    *(int4*)(xh + (size_t)i * 8) = w;
}

// ---- Pass 0c: W -> transposed bf16 hi/lo planes. Wt[n][k] = W[k][n]. ----
__global__ __launch_bounds__(256) void k_wsplit(
    const float* __restrict__ W, ushort* __restrict__ Wt_hi, ushort* __restrict__ Wt_lo)
{
    int idx = blockIdx.x * 256 + threadIdx.x;   // 65536
    if (idx >= D * D) return;
    int k = idx >> 8;
    int n = idx & 255;
    float f = W[idx];                // W[k][n], coalesced over n
    ushort h = bf16_rne(f);
    ushort l = bf16_rne(f - bf16_tof(h));
    Wt_hi[n * D + k] = h;
    Wt_lo[n * D + k] = l;
}

// ---- Pass 1: per-(row,colblock) counts + owner ----
__global__ __launch_bounds__(256) void k_count(
    const int* __restrict__ adj_row, const int* __restrict__ adj_col,
    const int* __restrict__ nodes, int* __restrict__ cellcnt, int* __restrict__ owner)
{
    int idx = blockIdx.x * 256 + threadIdx.x;
    if (idx < NE) {
        int row = adj_row[idx];
        int col = adj_col[idx];
        atomicAdd(&cellcnt[row * NB + (col >> CBSHIFT)], 1);
    }
    if (idx < N_SAMP) {
        atomicMax(&owner[nodes[idx]], idx);
    }
}

// ---- Pass 2: contiguous region per row, cb-sorted sub-offsets in-thread ----
__global__ __launch_bounds__(256) void k_rowalloc(
    const int* __restrict__ cellcnt, int* __restrict__ cellcur,
    int* __restrict__ rowptr, int* __restrict__ rowcnt, int* __restrict__ gtotal)
{
    int r = blockIdx.x * 256 + threadIdx.x;
    if (r >= N_SAMP) return;
    int pref[NB];
    int sum = 0;
    #pragma unroll
    for (int cb = 0; cb < NB; ++cb) {
        pref[cb] = sum;
        sum += cellcnt[r * NB + cb];
    }
    int base = atomicAdd(gtotal, sum);
    rowptr[r] = base;
    rowcnt[r] = sum;
    #pragma unroll
    for (int cb = 0; cb < NB; ++cb)
        cellcur[r * NB + cb] = base + pref[cb];
}

// ---- Pass 3: scatter packed {col, val} ----
__global__ __launch_bounds__(256) void k_scatter(
    const int* __restrict__ adj_row, const int* __restrict__ adj_col,
    const float* __restrict__ adj_val, int* __restrict__ cellcur, int2* __restrict__ bucket)
{
    int idx = blockIdx.x * 256 + threadIdx.x;
    if (idx >= NE) return;
    int row = adj_row[idx];
    int col = adj_col[idx];
    float val = adj_val[idx];
    int pos = atomicAdd(&cellcur[row * NB + (col >> CBSHIFT)], 1);
    bucket[pos] = make_int2(col, __float_as_int(val));
}

// ---- Pass 4: SpMM (fp16 x gather) + blend + owned new_y + fused decay rows ----
__global__ __launch_bounds__(256) void k_spmm_blend(
    const __half* __restrict__ xh, const int2* __restrict__ bucket,
    const int* __restrict__ rowptr, const int* __restrict__ rowcnt,
    const int* __restrict__ nodes, const int* __restrict__ owner,
    const float* __restrict__ y_buf, float* __restrict__ feat, float* __restrict__ newy)
{
    int wave = threadIdx.x >> 6;
    int lane = threadIdx.x & 63;
    int row  = blockIdx.x * 4 + wave;      // grid exact: always < N_SAMP
    int off  = lane * 4;

    int cnt = rowcnt[row];
    const int2* bk = bucket + rowptr[row];
    float4 acc = make_float4(0.f, 0.f, 0.f, 0.f);
    int j = 0;
    for (; j + 3 < cnt; j += 4) {
        int2 e0 = bk[j],     e1 = bk[j + 1];
        int2 e2 = bk[j + 2], e3 = bk[j + 3];
        float v0 = __int_as_float(e0.y), v1 = __int_as_float(e1.y);
        float v2 = __int_as_float(e2.y), v3 = __int_as_float(e3.y);
        float4 x0 = xload4h(xh + (size_t)e0.x * D + off);
        float4 x1 = xload4h(xh + (size_t)e1.x * D + off);
        float4 x2 = xload4h(xh + (size_t)e2.x * D + off);
        float4 x3 = xload4h(xh + (size_t)e3.x * D + off);
        acc.x += v0 * x0.x + v1 * x1.x + v2 * x2.x + v3 * x3.x;
        acc.y += v0 * x0.y + v1 * x1.y + v2 * x2.y + v3 * x3.y;
        acc.z += v0 * x0.z + v1 * x1.z + v2 * x2.z + v3 * x3.z;
        acc.w += v0 * x0.w + v1 * x1.w + v2 * x2.w + v3 * x3.w;
    }
    for (; j < cnt; ++j) {
        int2 e0 = bk[j];
        float v0 = __int_as_float(e0.y);
        float4 x0 = xload4h(xh + (size_t)e0.x * D + off);
        acc.x += v0 * x0.x; acc.y += v0 * x0.y;
        acc.z += v0 * x0.z; acc.w += v0 * x0.w;
    }
    int node = nodes[row];
    float4 yv = ntload4(y_buf + (size_t)node * D + off);
    float4 f;
    f.x = 0.9f * yv.x + 0.1f * acc.x;
    f.y = 0.9f * yv.y + 0.1f * acc.y;
    f.z = 0.9f * yv.z + 0.1f * acc.z;
    f.w = 0.9f * yv.w + 0.1f * acc.w;
    *(float4*)(feat + (size_t)row * D + off) = f;
    if (owner[node] == row)
        ntstore4(newy + (size_t)node * D + off, f);

    // fused decay rows (owner < 0): wave `row` owns newy rows 4row..4row+3
    int base = row * 4;
    int4 ow = *(const int4*)&owner[base];
    #pragma unroll
    for (int k = 0; k < 4; ++k) {
        int o = (k == 0) ? ow.x : (k == 1) ? ow.y : (k == 2) ? ow.z : ow.w;
        if (o < 0) {
            int r = base + k;
            float4 y = ntload4(y_buf + (size_t)r * D + off);
            ntstore4(newy + (size_t)r * D + off,
                     make_float4(0.9f * y.x, 0.9f * y.y, 0.9f * y.z, 0.9f * y.w));
        }
    }
}

// ---- Pass 5: MFMA gemm (3-term bf16 split) + bias + ELU + row-norm, fused ----
// Block: 32 rows x 256 cols, 4 waves. Wave w: M-tile mt=w&1 (16 rows),
// N-half nh=w>>1 (128 cols = 8 n-tiles). K loop: 8 steps of 32.
// C/D layout (verified m89): col = lane&15, row = 4*(lane>>4) + reg.
__global__ __launch_bounds__(256) void k_gemm_elu_norm(
    float* __restrict__ io, const ushort* __restrict__ Wt_hi,
    const ushort* __restrict__ Wt_lo, const float* __restrict__ b,
    const float* __restrict__ scale, const float* __restrict__ offset)
{
    // padded rows: F stride 264 (528 B -> word stride 132 ≡ 4 mod 32: 2-way, free)
    //              W stride 40  (80 B  -> word stride 20  ≡ 20 mod 32: 2-way, free)
    __shared__ ushort Fhi[32][264], Flo[32][264];
    __shared__ ushort Wh[256][40],  Wl[256][40];
    __shared__ float  red[2][2][16][2];

    int tid  = threadIdx.x;
    int w    = tid >> 6;
    int l    = tid & 63;
    int g    = l >> 4;        // k-group / D-row-group
    int c16  = l & 15;        // col within 16-tile / A-row within 16-tile
    int mt   = w & 1;
    int nh   = w >> 1;
    int r0   = blockIdx.x * 32;

    // ---- stage feat tile, split to bf16 hi/lo ----
    {
        int m  = tid >> 3;            // 32 rows, 8 threads/row
        int c0 = (tid & 7) * 32;      // 32 cols each
        int r  = r0 + m;
        #pragma unroll
        for (int i = 0; i < 8; ++i) {
            float4 v = (r < N_SAMP) ? ntload4(io + (size_t)r * D + c0 + i * 4)
                                    : make_float4(0.f, 0.f, 0.f, 0.f);
            ushort h0 = bf16_rne(v.x), h1 = bf16_rne(v.y);
            ushort h2 = bf16_rne(v.z), h3 = bf16_rne(v.w);
            ushort l0 = bf16_rne(v.x - bf16_tof(h0));
            ushort l1 = bf16_rne(v.y - bf16_tof(h1));
            ushort l2 = bf16_rne(v.z - bf16_tof(h2));
            ushort l3 = bf16_rne(v.w - bf16_tof(h3));
            int c = c0 + i * 4;
            uint2 ph, pl;
            ph.x = (uint)h0 | ((uint)h1 << 16); ph.y = (uint)h2 | ((uint)h3 << 16);
            pl.x = (uint)l0 | ((uint)l1 << 16); pl.y = (uint)l2 | ((uint)l3 << 16);
            *(uint2*)&Fhi[m][c] = ph;
            *(uint2*)&Flo[m][c] = pl;
        }
    }

    f32x4v acc[8];
    #pragma unroll
    for (int t = 0; t < 8; ++t) acc[t] = (f32x4v)(0.f);

    for (int kt8 = 0; kt8 < 8; ++kt8) {
        int kt = kt8 * 32;
        __syncthreads();   // covers F staging at kt8==0; W reuse hazard otherwise
        {
            int n = tid;   // 256 threads = 256 n-rows; 32 k's (64 B) each plane
            const int4* gh = (const int4*)(Wt_hi + (size_t)n * D + kt);
            const int4* gl = (const int4*)(Wt_lo + (size_t)n * D + kt);
            #pragma unroll
            for (int i = 0; i < 4; ++i) {
                *(int4*)&Wh[n][i * 8] = gh[i];
                *(int4*)&Wl[n][i * 8] = gl[i];
            }
        }
        __syncthreads();
        int arow = mt * 16 + c16;
        bf16x8 ah = *(const bf16x8*)&Fhi[arow][kt + g * 8];
        bf16x8 al = *(const bf16x8*)&Flo[arow][kt + g * 8];
        #pragma unroll
        for (int t = 0; t < 8; ++t) {
            int n = nh * 128 + t * 16 + c16;
            bf16x8 bh = *(const bf16x8*)&Wh[n][g * 8];
            bf16x8 bl = *(const bf16x8*)&Wl[n][g * 8];
            acc[t] = __builtin_amdgcn_mfma_f32_16x16x32_bf16(ah, bh, acc[t], 0, 0, 0);
            acc[t] = __builtin_amdgcn_mfma_f32_16x16x32_bf16(al, bh, acc[t], 0, 0, 0);
            acc[t] = __builtin_amdgcn_mfma_f32_16x16x32_bf16(ah, bl, acc[t], 0, 0, 0);
        }
    }

    // ---- epilogue: bias, ELU, row-norm ----
    float bcol[8], scol[8], ocol[8];
    #pragma unroll
    for (int t = 0; t < 8; ++t) {
        int c = nh * 128 + t * 16 + c16;
        bcol[t] = b[c]; scol[t] = scale[c]; ocol[t] = offset[c];
    }
    float s[4] = {0.f, 0.f, 0.f, 0.f};
    float q[4] = {0.f, 0.f, 0.f, 0.f};
    #pragma unroll
    for (int t = 0; t < 8; ++t) {
        #pragma unroll
        for (int j = 0; j < 4; ++j) {
            float o = acc[t][j] + bcol[t];
            o = o > 0.f ? o : expf(o) - 1.f;
            acc[t][j] = o;
            s[j] += o;
            q[j] += o * o;
        }
    }
    #pragma unroll
    for (int j = 0; j < 4; ++j) {
        #pragma unroll
        for (int d2 = 1; d2 < 16; d2 <<= 1) {   // reduce within 16-lane col group
            s[j] += __shfl_xor(s[j], d2, 64);
            q[j] += __shfl_xor(q[j], d2, 64);
        }
    }
    if (c16 == 0) {
        #pragma unroll
        for (int j = 0; j < 4; ++j) {
            red[mt][nh][g * 4 + j][0] = s[j];
            red[mt][nh][g * 4 + j][1] = q[j];
        }
    }
    __syncthreads();
    #pragma unroll
    for (int j = 0; j < 4; ++j) {
        int rr = g * 4 + j;
        float S = red[mt][0][rr][0] + red[mt][1][rr][0];
        float Q = red[mt][0][rr][1] + red[mt][1][rr][1];
        float mean = S * (1.0f / 256.0f);
        float var  = Q * (1.0f / 256.0f) - mean * mean + 1e-9f;
        float rstd = rsqrtf(var);
        int r = r0 + mt * 16 + rr;
        if (r < N_SAMP) {
            #pragma unroll
            for (int t = 0; t < 8; ++t) {
                int c = nh * 128 + t * 16 + c16;
                io[(size_t)r * D + c] = (acc[t][j] - mean) * scol[t] * rstd + ocol[t];
            }
        }
    }
}

extern "C" void kernel_launch(void* const* d_in, const int* in_sizes, int n_in,
                              void* d_out, int out_size, void* d_ws, size_t ws_size,
                              hipStream_t stream) {
    const float* x       = (const float*)d_in[0];
    const int*   adj_row = (const int*)  d_in[1];
    const int*   adj_col = (const int*)  d_in[2];
    const float* adj_val = (const float*)d_in[3];
    const int*   nodes   = (const int*)  d_in[4];
    const float* y_buf   = (const float*)d_in[5];
    const float* Wm      = (const float*)d_in[6];
    const float* b       = (const float*)d_in[7];
    const float* scale   = (const float*)d_in[8];
    const float* offset  = (const float*)d_in[9];

    float* out  = (float*)d_out;                  // [N_SAMP, D] (feat staged here first)
    float* newy = out + (size_t)N_SAMP * D;       // [N_TOTAL, D]

    // workspace layout
    char*   ws      = (char*)d_ws;
    int*    cellcnt = (int*)(ws);                                 // 2.6 MB
    int*    cellcur = (int*)(ws + 3  * 1024 * 1024);              // 2.6 MB
    int*    rowptr  = (int*)(ws + 6  * 1024 * 1024);              // 200 KB
    int*    rowcnt  = (int*)(ws + 6  * 1024 * 1024 + 256 * 1024);
    int*    gtotal  = (int*)(ws + 6  * 1024 * 1024 + 512 * 1024);
    int*    owner   = (int*)(ws + 7  * 1024 * 1024);              // 800 KB
    ushort* Wt_hi   = (ushort*)(ws + 8 * 1024 * 1024);            // 128 KB
    ushort* Wt_lo   = (ushort*)(ws + 8 * 1024 * 1024 + 256 * 1024);
    int2*   bucket  = (int2*)(ws + 9 * 1024 * 1024);              // 12.8 MB
    __half* xh      = (__half*)(ws + 22 * 1024 * 1024);           // 25.6 MB

    k_init    <<<(NCELL + 255) / 256,      256, 0, stream>>>(cellcnt, owner, gtotal);
    k_prep    <<<(N_SRC * D / 8 + 255) / 256, 256, 0, stream>>>(x, xh);
    k_wsplit  <<<(D * D + 255) / 256,      256, 0, stream>>>(Wm, Wt_hi, Wt_lo);
    k_count   <<<(NE + 255) / 256,         256, 0, stream>>>(adj_row, adj_col, nodes, cellcnt, owner);
    k_rowalloc<<<(N_SAMP + 255) / 256,     256, 0, stream>>>(cellcnt, cellcur, rowptr, rowcnt, gtotal);
    k_scatter <<<(NE + 255) / 256,         256, 0, stream>>>(adj_row, adj_col, adj_val, cellcur, bucket);
    k_spmm_blend<<<N_SAMP / 4, 256, 0, stream>>>(
        xh, bucket, rowptr, rowcnt, nodes, owner, y_buf, out, newy);
    k_gemm_elu_norm<<<(N_SAMP + 31) / 32, 256, 0, stream>>>(out, Wt_hi, Wt_lo, b, scale, offset);
}

// Round 5
// 786.879 us; speedup vs baseline: 1.4010x; 1.0637x over previous
//
#include <hip/hip_runtime.h>
#include <hip/hip_fp16.h>
#include <math.h>

#define N_SRC   50000
#define N_SAMP  50000
#define N_TOTAL 200000
#define NE      1600000
#define D       256

// Edges sorted by (row, col>>CBSHIFT), stored contiguously per row (4-padded).
#define CBSHIFT 11
#define NB      25                 // ceil(50000 / 2048)
#define NCELL   (N_SAMP * NB)      // 1.25M

typedef unsigned short ushort;
typedef unsigned int   uint;
using bf16x8 = __attribute__((ext_vector_type(8))) short;
using f32x4v = __attribute__((ext_vector_type(4))) float;

// ---- nontemporal helpers: ONLY for one-way streams (writes, read-once) ----
__device__ __forceinline__ float4 ntload4(const float* p) {
    f32x4v t = __builtin_nontemporal_load((const f32x4v*)p);
    return make_float4(t.x, t.y, t.z, t.w);
}
__device__ __forceinline__ void ntstore4(float* p, float4 v) {
    f32x4v t; t.x = v.x; t.y = v.y; t.z = v.z; t.w = v.w;
    __builtin_nontemporal_store(t, (f32x4v*)p);
}

// ---- bf16 round-to-nearest-even split helpers ----
__device__ __forceinline__ ushort bf16_rne(float f) {
    uint u = __float_as_uint(f);
    uint r = u + 0x7FFFu + ((u >> 16) & 1u);
    return (ushort)(r >> 16);
}
__device__ __forceinline__ float bf16_tof(ushort h) {
    return __uint_as_float(((uint)h) << 16);
}

// ---- fp16 x gather load: 8 B/lane -> float4 (plain load: keep xh LLC-resident) ----
__device__ __forceinline__ float4 xload4h(const __half* p) {
    int2 r = *(const int2*)p;
    __half2 h0 = *(__half2*)&r.x;
    __half2 h1 = *(__half2*)&r.y;
    float2 f0 = __half22float2(h0);
    float2 f1 = __half22float2(h1);
    return make_float4(f0.x, f0.y, f1.x, f1.y);
}

// ---- packed edge: low16 = col, high16 = fp16 val ----
__device__ __forceinline__ void eunpack(uint e, int& col, float& val) {
    col = (int)(e & 0xFFFFu);
    val = __half2float(__ushort_as_half((ushort)(e >> 16)));
}

// ---- Pass 0: fused setup = init + x->fp16 + W split/transpose ----
__global__ __launch_bounds__(256) void k_setup(
    int* __restrict__ cellcnt, int* __restrict__ owner, int* __restrict__ gtotal,
    const float* __restrict__ x, __half* __restrict__ xh,
    const float* __restrict__ W, ushort* __restrict__ Wt_hi, ushort* __restrict__ Wt_lo)
{
    int i = blockIdx.x * 256 + threadIdx.x;   // grid: 1.6M threads
    if (i < NCELL)   cellcnt[i] = 0;
    if (i < N_TOTAL) owner[i]   = -1;
    if (i == 0)      *gtotal    = 0;
    if (i < (N_SRC * D) / 8) {                // x -> fp16, 8 elems/thread
        float4 a = ntload4(x + (size_t)i * 8);        // read-once: NT
        float4 c = ntload4(x + (size_t)i * 8 + 4);
        __half2 h0 = __floats2half2_rn(a.x, a.y);
        __half2 h1 = __floats2half2_rn(a.z, a.w);
        __half2 h2 = __floats2half2_rn(c.x, c.y);
        __half2 h3 = __floats2half2_rn(c.z, c.w);
        int4 w;
        w.x = *(int*)&h0; w.y = *(int*)&h1; w.z = *(int*)&h2; w.w = *(int*)&h3;
        *(int4*)(xh + (size_t)i * 8) = w;             // plain store: allocate
    }
    if (i < D * D) {                          // W -> transposed bf16 hi/lo
        int k = i >> 8;
        int n = i & 255;
        float f = W[i];
        ushort h = bf16_rne(f);
        ushort l = bf16_rne(f - bf16_tof(h));
        Wt_hi[n * D + k] = h;
        Wt_lo[n * D + k] = l;
    }
}

// ---- Pass 1: per-(row,colblock) counts + owner ----
__global__ __launch_bounds__(256) void k_count(
    const int* __restrict__ adj_row, const int* __restrict__ adj_col,
    const int* __restrict__ nodes, int* __restrict__ cellcnt, int* __restrict__ owner)
{
    int idx = blockIdx.x * 256 + threadIdx.x;
    if (idx < NE) {
        int row = __builtin_nontemporal_load(adj_row + idx);
        int col = __builtin_nontemporal_load(adj_col + idx);
        atomicAdd(&cellcnt[row * NB + (col >> CBSHIFT)], 1);
    }
    if (idx < N_SAMP) {
        atomicMax(&owner[nodes[idx]], idx);
    }
}

// ---- Pass 2: contiguous 4-padded region per row, cb-sorted sub-offsets ----
__global__ __launch_bounds__(256) void k_rowalloc(
    const int* __restrict__ cellcnt, int* __restrict__ cellcur,
    int* __restrict__ rowptr, int* __restrict__ rowcnt, int* __restrict__ gtotal)
{
    int r = blockIdx.x * 256 + threadIdx.x;
    if (r >= N_SAMP) return;
    int pref[NB];
    int sum = 0;
    #pragma unroll
    for (int cb = 0; cb < NB; ++cb) {
        pref[cb] = sum;
        sum += cellcnt[r * NB + cb];
    }
    int base = atomicAdd(gtotal, (sum + 3) & ~3);   // 16 B-aligned regions
    rowptr[r] = base;
    rowcnt[r] = sum;
    #pragma unroll
    for (int cb = 0; cb < NB; ++cb)
        cellcur[r * NB + cb] = base + pref[cb];
}

// ---- Pass 3: scatter packed 4 B edges ----
__global__ __launch_bounds__(256) void k_scatter(
    const int* __restrict__ adj_row, const int* __restrict__ adj_col,
    const float* __restrict__ adj_val, int* __restrict__ cellcur, uint* __restrict__ bucket)
{
    int idx = blockIdx.x * 256 + threadIdx.x;
    if (idx >= NE) return;
    int   row = __builtin_nontemporal_load(adj_row + idx);
    int   col = __builtin_nontemporal_load(adj_col + idx);
    float val = __builtin_nontemporal_load(adj_val + idx);
    uint  e   = (uint)col | ((uint)__half_as_ushort(__float2half_rn(val)) << 16);
    int pos = atomicAdd(&cellcur[row * NB + (col >> CBSHIFT)], 1);
    bucket[pos] = e;
}

// ---- Pass 4: SpMM (fp16 x, 4 B edges) + blend + owned new_y + decay rows ----
__global__ __launch_bounds__(256) void k_spmm_blend(
    const __half* __restrict__ xh, const uint* __restrict__ bucket,
    const int* __restrict__ rowptr, const int* __restrict__ rowcnt,
    const int* __restrict__ nodes, const int* __restrict__ owner,
    const float* __restrict__ y_buf, float* __restrict__ feat, float* __restrict__ newy)
{
    int wave = threadIdx.x >> 6;
    int lane = threadIdx.x & 63;
    int row  = blockIdx.x * 4 + wave;      // grid exact: always < N_SAMP
    int off  = lane * 4;

    int cnt = rowcnt[row];
    const uint* bk = bucket + rowptr[row];     // 16 B aligned
    float4 acc = make_float4(0.f, 0.f, 0.f, 0.f);
    int j = 0;
    for (; j + 3 < cnt; j += 4) {
        uint4 ev = *(const uint4*)(bk + j);
        int c0, c1, c2, c3; float v0, v1, v2, v3;
        eunpack(ev.x, c0, v0); eunpack(ev.y, c1, v1);
        eunpack(ev.z, c2, v2); eunpack(ev.w, c3, v3);
        float4 x0 = xload4h(xh + (size_t)c0 * D + off);
        float4 x1 = xload4h(xh + (size_t)c1 * D + off);
        float4 x2 = xload4h(xh + (size_t)c2 * D + off);
        float4 x3 = xload4h(xh + (size_t)c3 * D + off);
        acc.x += v0 * x0.x + v1 * x1.x + v2 * x2.x + v3 * x3.x;
        acc.y += v0 * x0.y + v1 * x1.y + v2 * x2.y + v3 * x3.y;
        acc.z += v0 * x0.z + v1 * x1.z + v2 * x2.z + v3 * x3.z;
        acc.w += v0 * x0.w + v1 * x1.w + v2 * x2.w + v3 * x3.w;
    }
    for (; j < cnt; ++j) {
        int c0; float v0;
        eunpack(bk[j], c0, v0);
        float4 x0 = xload4h(xh + (size_t)c0 * D + off);
        acc.x += v0 * x0.x; acc.y += v0 * x0.y;
        acc.z += v0 * x0.z; acc.w += v0 * x0.w;
    }
    int node = nodes[row];
    // PLAIN load: y_buf (205 MB) is the LLC-resident set — let it cache.
    float4 yv = *(const float4*)(y_buf + (size_t)node * D + off);
    float4 f;
    f.x = 0.9f * yv.x + 0.1f * acc.x;
    f.y = 0.9f * yv.y + 0.1f * acc.y;
    f.z = 0.9f * yv.z + 0.1f * acc.z;
    f.w = 0.9f * yv.w + 0.1f * acc.w;
    *(float4*)(feat + (size_t)row * D + off) = f;   // re-read by gemm: cache
    if (owner[node] == row)
        ntstore4(newy + (size_t)node * D + off, f); // one-way stream: NT

    // fused decay rows (owner < 0): wave `row` owns newy rows 4row..4row+3
    int base = row * 4;
    int4 ow = *(const int4*)&owner[base];
    #pragma unroll
    for (int k = 0; k < 4; ++k) {
        int o = (k == 0) ? ow.x : (k == 1) ? ow.y : (k == 2) ? ow.z : ow.w;
        if (o < 0) {
            int r = base + k;
            float4 y = *(const float4*)(y_buf + (size_t)r * D + off);  // plain: resident
            ntstore4(newy + (size_t)r * D + off,
                     make_float4(0.9f * y.x, 0.9f * y.y, 0.9f * y.z, 0.9f * y.w));
        }
    }
}

// ---- Pass 5: MFMA gemm (3-term bf16 split) + bias + ELU + row-norm, fused ----
__global__ __launch_bounds__(256) void k_gemm_elu_norm(
    float* __restrict__ io, const ushort* __restrict__ Wt_hi,
    const ushort* __restrict__ Wt_lo, const float* __restrict__ b,
    const float* __restrict__ scale, const float* __restrict__ offset)
{
    __shared__ ushort Fhi[32][264], Flo[32][264];
    __shared__ ushort Wh[256][40],  Wl[256][40];
    __shared__ float  red[2][2][16][2];

    int tid  = threadIdx.x;
    int w    = tid >> 6;
    int l    = tid & 63;
    int g    = l >> 4;
    int c16  = l & 15;
    int mt   = w & 1;
    int nh   = w >> 1;
    int r0   = blockIdx.x * 32;

    {
        int m  = tid >> 3;
        int c0 = (tid & 7) * 32;
        int r  = r0 + m;
        #pragma unroll
        for (int i = 0; i < 8; ++i) {
            float4 v = (r < N_SAMP) ? *(const float4*)(io + (size_t)r * D + c0 + i * 4)
                                    : make_float4(0.f, 0.f, 0.f, 0.f);
            ushort h0 = bf16_rne(v.x), h1 = bf16_rne(v.y);
            ushort h2 = bf16_rne(v.z), h3 = bf16_rne(v.w);
            ushort l0 = bf16_rne(v.x - bf16_tof(h0));
            ushort l1 = bf16_rne(v.y - bf16_tof(h1));
            ushort l2 = bf16_rne(v.z - bf16_tof(h2));
            ushort l3 = bf16_rne(v.w - bf16_tof(h3));
            int c = c0 + i * 4;
            uint2 ph, pl;
            ph.x = (uint)h0 | ((uint)h1 << 16); ph.y = (uint)h2 | ((uint)h3 << 16);
            pl.x = (uint)l0 | ((uint)l1 << 16); pl.y = (uint)l2 | ((uint)l3 << 16);
            *(uint2*)&Fhi[m][c] = ph;
            *(uint2*)&Flo[m][c] = pl;
        }
    }

    f32x4v acc[8];
    #pragma unroll
    for (int t = 0; t < 8; ++t) acc[t] = (f32x4v)(0.f);

    for (int kt8 = 0; kt8 < 8; ++kt8) {
        int kt = kt8 * 32;
        __syncthreads();
        {
            int n = tid;
            const int4* gh = (const int4*)(Wt_hi + (size_t)n * D + kt);
            const int4* gl = (const int4*)(Wt_lo + (size_t)n * D + kt);
            #pragma unroll
            for (int i = 0; i < 4; ++i) {
                *(int4*)&Wh[n][i * 8] = gh[i];
                *(int4*)&Wl[n][i * 8] = gl[i];
            }
        }
        __syncthreads();
        int arow = mt * 16 + c16;
        bf16x8 ah = *(const bf16x8*)&Fhi[arow][kt + g * 8];
        bf16x8 al = *(const bf16x8*)&Flo[arow][kt + g * 8];
        #pragma unroll
        for (int t = 0; t < 8; ++t) {
            int n = nh * 128 + t * 16 + c16;
            bf16x8 bh = *(const bf16x8*)&Wh[n][g * 8];
            bf16x8 bl = *(const bf16x8*)&Wl[n][g * 8];
            acc[t] = __builtin_amdgcn_mfma_f32_16x16x32_bf16(ah, bh, acc[t], 0, 0, 0);
            acc[t] = __builtin_amdgcn_mfma_f32_16x16x32_bf16(al, bh, acc[t], 0, 0, 0);
            acc[t] = __builtin_amdgcn_mfma_f32_16x16x32_bf16(ah, bl, acc[t], 0, 0, 0);
        }
    }

    float bcol[8], scol[8], ocol[8];
    #pragma unroll
    for (int t = 0; t < 8; ++t) {
        int c = nh * 128 + t * 16 + c16;
        bcol[t] = b[c]; scol[t] = scale[c]; ocol[t] = offset[c];
    }
    float s[4] = {0.f, 0.f, 0.f, 0.f};
    float q[4] = {0.f, 0.f, 0.f, 0.f};
    #pragma unroll
    for (int t = 0; t < 8; ++t) {
        #pragma unroll
        for (int j = 0; j < 4; ++j) {
            float o = acc[t][j] + bcol[t];
            o = o > 0.f ? o : expf(o) - 1.f;
            acc[t][j] = o;
            s[j] += o;
            q[j] += o * o;
        }
    }
    #pragma unroll
    for (int j = 0; j < 4; ++j) {
        #pragma unroll
        for (int d2 = 1; d2 < 16; d2 <<= 1) {
            s[j] += __shfl_xor(s[j], d2, 64);
            q[j] += __shfl_xor(q[j], d2, 64);
        }
    }
    if (c16 == 0) {
        #pragma unroll
        for (int j = 0; j < 4; ++j) {
            red[mt][nh][g * 4 + j][0] = s[j];
            red[mt][nh][g * 4 + j][1] = q[j];
        }
    }
    __syncthreads();
    #pragma unroll
    for (int j = 0; j < 4; ++j) {
        int rr = g * 4 + j;
        float S = red[mt][0][rr][0] + red[mt][1][rr][0];
        float Q = red[mt][0][rr][1] + red[mt][1][rr][1];
        float mean = S * (1.0f / 256.0f);
        float var  = Q * (1.0f / 256.0f) - mean * mean + 1e-9f;
        float rstd = rsqrtf(var);
        int r = r0 + mt * 16 + rr;
        if (r < N_SAMP) {
            #pragma unroll
            for (int t = 0; t < 8; ++t) {
                int c = nh * 128 + t * 16 + c16;
                io[(size_t)r * D + c] = (acc[t][j] - mean) * scol[t] * rstd + ocol[t];
            }
        }
    }
}

extern "C" void kernel_launch(void* const* d_in, const int* in_sizes, int n_in,
                              void* d_out, int out_size, void* d_ws, size_t ws_size,
                              hipStream_t stream) {
    const float* x       = (const float*)d_in[0];
    const int*   adj_row = (const int*)  d_in[1];
    const int*   adj_col = (const int*)  d_in[2];
    const float* adj_val = (const float*)d_in[3];
    const int*   nodes   = (const int*)  d_in[4];
    const float* y_buf   = (const float*)d_in[5];
    const float* Wm      = (const float*)d_in[6];
    const float* b       = (const float*)d_in[7];
    const float* scale   = (const float*)d_in[8];
    const float* offset  = (const float*)d_in[9];

    float* out  = (float*)d_out;                  // [N_SAMP, D] (feat staged here first)
    float* newy = out + (size_t)N_SAMP * D;       // [N_TOTAL, D]

    // workspace layout (≈ 45.6 MB)
    char*   ws      = (char*)d_ws;
    int*    cellcnt = (int*)(ws);                                  // 5 MB
    int*    cellcur = (int*)(ws + 5  * 1024 * 1024);               // 5 MB
    int*    rowptr  = (int*)(ws + 10 * 1024 * 1024);               // 200 KB
    int*    rowcnt  = (int*)(ws + 10 * 1024 * 1024 + 256 * 1024);
    int*    gtotal  = (int*)(ws + 10 * 1024 * 1024 + 512 * 1024);
    int*    owner   = (int*)(ws + 11 * 1024 * 1024);               // 800 KB
    ushort* Wt_hi   = (ushort*)(ws + 12 * 1024 * 1024);            // 128 KB
    ushort* Wt_lo   = (ushort*)(ws + 12 * 1024 * 1024 + 128 * 1024);
    uint*   bucket  = (uint*)(ws + 13 * 1024 * 1024);              // 7 MB (NE + pad)
    __half* xh      = (__half*)(ws + 20 * 1024 * 1024);            // 25.6 MB

    int setup_threads = (N_SRC * D) / 8;   // 1.6M (covers NCELL, N_TOTAL, D*D)
    k_setup   <<<(setup_threads + 255) / 256, 256, 0, stream>>>(
        cellcnt, owner, gtotal, x, xh, Wm, Wt_hi, Wt_lo);
    k_count   <<<(NE + 255) / 256,     256, 0, stream>>>(adj_row, adj_col, nodes, cellcnt, owner);
    k_rowalloc<<<(N_SAMP + 255) / 256, 256, 0, stream>>>(cellcnt, cellcur, rowptr, rowcnt, gtotal);
    k_scatter <<<(NE + 255) / 256,     256, 0, stream>>>(adj_row, adj_col, adj_val, cellcur, bucket);
    k_spmm_blend<<<N_SAMP / 4, 256, 0, stream>>>(
        xh, bucket, rowptr, rowcnt, nodes, owner, y_buf, out, newy);
    k_gemm_elu_norm<<<(N_SAMP + 31) / 32, 256, 0, stream>>>(out, Wt_hi, Wt_lo, b, scale, offset);
}